// Round 7
// baseline (120.191 us; speedup 1.0000x reference)
//
#include <hip/hip_runtime.h>
#include <hip/hip_bf16.h>
#include <hip/hip_fp16.h>

// Problem constants (fixed by reference setup_inputs)
constexpr int B_ = 4, C_ = 256, H_ = 200, W_ = 336;
constexpr int OH_ = 7, OW_ = 7;
constexpr float SCALE_ = 0.25f;
constexpr int HW_ = H_ * W_;          // 67200
constexpr int OHW_ = OH_ * OW_;       // 49
constexpr int CH_ = 128;              // channels per gather block (C_/2)
constexpr int PB_ = 2;                // batches per phase

typedef float f32x4 __attribute__((ext_vector_type(4)));

// ---------------------------------------------------------------------------
// Kernel 1: transpose+downconvert batches [b0, b0+PB_) of (B, C, H*W) fp32
// into a PB_-batch fp16 (b_local, H*W, C) buffer (69 MB). The buffer is
// REUSED at the same addresses across phases so its lines stay (dirty) in
// the 256 MB memory-side L3: the gather reads hit L3, and phase 2's
// overwrite re-dirties lines in place instead of forcing HBM writebacks.
// feat reads are nontemporal (streamed once; don't evict featT).
// ---------------------------------------------------------------------------
__global__ __launch_bounds__(256) void transpose_bchw_bhwc_f16(
    const float* __restrict__ in, __half* __restrict__ out, int b0) {
  __shared__ unsigned int tileu[32][68];  // [k][cu]; uint = 2 channels
  const int bz = blockIdx.z;        // batch-local 0..PB_-1
  const int k0 = blockIdx.x * 32;   // spatial tile origin
  const int c0 = blockIdx.y * 128;  // channel tile origin
  const float* src = in + (size_t)(b0 + bz) * C_ * HW_;
  unsigned int* dst = (unsigned int*)(out + (size_t)bz * HW_ * C_);

  const int tx = threadIdx.x & 31;  // k within tile
  const int rp = threadIdx.x >> 5;  // 0..7
#pragma unroll
  for (int i = 0; i < 8; ++i) {
    const int cu = rp * 8 + i;      // channel pair 0..63
    const float a = __builtin_nontemporal_load(
        &src[(size_t)(c0 + 2 * cu) * HW_ + k0 + tx]);
    const float c = __builtin_nontemporal_load(
        &src[(size_t)(c0 + 2 * cu + 1) * HW_ + k0 + tx]);
    const __half2 h = __halves2half2(__float2half(a), __float2half(c));
    tileu[tx][cu] = *(const unsigned int*)&h;
  }
  __syncthreads();

  const int q  = threadIdx.x & 15;  // uint4 index within k-row
  const int kk = threadIdx.x >> 4;  // 0..15
#pragma unroll
  for (int p = 0; p < 2; ++p) {
    const int k = kk + p * 16;
    const uint4 v = *(const uint4*)&tileu[k][4 * q];
    *(uint4*)&dst[(size_t)(k0 + k) * (C_ / 2) + (c0 / 2) + 4 * q] = v;
  }
}

// ---------------------------------------------------------------------------
// Kernel 2: RoIAlign gather (phase b0): only ROIs with bidx in
// [b0, b0+PB_) proceed (block-uniform early exit). Grid (nrois, 2):
// block = one ROI x 128 channels. Threads 0..48 precompute corner offsets
// + valid-folded bilinear weights; lane cp=0..63 owns local channel pair,
// 4 waves stride the 49 samples. Corner loads are 512B/wave, L3-resident.
// Stage in vals[c_local*49+s], stream out linear nontemporal f32x4 into
// out[n][ch0+c][s] ((N, C, OH, OW) layout).
// ---------------------------------------------------------------------------
__global__ __launch_bounds__(256) void roi_gather_T_f16(
    const __half* __restrict__ featT, const float* __restrict__ rois,
    const int* __restrict__ bidx, float* __restrict__ out, int b0) {
  __shared__ float vals[CH_ * OHW_];  // 25088 B
  __shared__ int   offs[4][OHW_];     // corner pixel index (y*W+x)
  __shared__ float wts[4][OHW_];      // bilinear weights, valid-folded
  const int n = blockIdx.x;
  const int b = bidx[n];              // block-uniform
  if (b < b0 || b >= b0 + PB_) return;
  const int ch0 = blockIdx.y * CH_;   // channel half origin (0 or 128)
  const int t   = threadIdx.x;

  if (t < OHW_) {
    const int s = t, oh = s / OW_, ow = s - oh * OW_;
    const float x1 = rois[n * 4 + 0] * SCALE_ - 0.5f;
    const float y1 = rois[n * 4 + 1] * SCALE_ - 0.5f;
    const float x2 = rois[n * 4 + 2] * SCALE_ - 0.5f;
    const float y2 = rois[n * 4 + 3] * SCALE_ - 0.5f;
    const float bw = (x2 - x1) * (1.0f / OW_);
    const float bh = (y2 - y1) * (1.0f / OH_);
    const float x = x1 + ((float)ow + 0.5f) * bw;
    const float y = y1 + ((float)oh + 0.5f) * bh;
    const bool valid =
        (y >= -1.0f) & (y <= (float)H_) & (x >= -1.0f) & (x <= (float)W_);
    const float xc = fminf(fmaxf(x, 0.0f), (float)(W_ - 1));
    const float yc = fminf(fmaxf(y, 0.0f), (float)(H_ - 1));
    const int xl = (int)xc, yl = (int)yc;
    const int xh = min(xl + 1, W_ - 1), yh = min(yl + 1, H_ - 1);
    const float lx = xc - (float)xl, ly = yc - (float)yl;
    const float hx = 1.0f - lx, hy = 1.0f - ly;
    const float vm = valid ? 1.0f : 0.0f;
    offs[0][s] = yl * W_ + xl;  wts[0][s] = vm * hy * hx;
    offs[1][s] = yl * W_ + xh;  wts[1][s] = vm * hy * lx;
    offs[2][s] = yh * W_ + xl;  wts[2][s] = vm * ly * hx;
    offs[3][s] = yh * W_ + xh;  wts[3][s] = vm * ly * lx;
  }
  __syncthreads();

  const __half2* fb2 =
      (const __half2*)(featT + (size_t)(b - b0) * HW_ * C_) + (ch0 >> 1);
  const int cp = t & 63;   // local channel pair -> channels 2cp, 2cp+1
  const int sh = t >> 6;   // sample phase 0..3 (wave-uniform)

#pragma unroll 2
  for (int i = 0; i < 13; ++i) {
    const int s = 4 * i + sh;
    if (s < OHW_) {
      const float w0 = wts[0][s], w1 = wts[1][s];
      const float w2 = wts[2][s], w3 = wts[3][s];
      const __half2 a0 = fb2[(size_t)offs[0][s] * (C_ / 2) + cp];
      const __half2 a1 = fb2[(size_t)offs[1][s] * (C_ / 2) + cp];
      const __half2 a2 = fb2[(size_t)offs[2][s] * (C_ / 2) + cp];
      const __half2 a3 = fb2[(size_t)offs[3][s] * (C_ / 2) + cp];
      const float2 f0 = __half22float2(a0), f1 = __half22float2(a1);
      const float2 f2 = __half22float2(a2), f3 = __half22float2(a3);
      vals[(2 * cp)     * OHW_ + s] =
          w0 * f0.x + w1 * f1.x + w2 * f2.x + w3 * f3.x;
      vals[(2 * cp + 1) * OHW_ + s] =
          w0 * f0.y + w1 * f1.y + w2 * f2.y + w3 * f3.y;
    }
  }
  __syncthreads();

  // Stream out 6272 floats (= 1568 f32x4) -> out[n][ch0..ch0+127][:],
  // contiguous, nontemporal (never re-read; protect featT in L3).
  const f32x4* v4 = (const f32x4*)vals;
  float* po = out + (size_t)n * (C_ * OHW_) + (size_t)ch0 * OHW_;
#pragma unroll
  for (int p = 0; p < 7; ++p) {
    const int idx = p * 256 + t;
    if (idx < (CH_ * OHW_) / 4) {
      __builtin_nontemporal_store(v4[idx], (f32x4*)&po[idx * 4]);
    }
  }
}

// ---------------------------------------------------------------------------
// Fallback (only if ws too small): gather straight from (B, C, H, W) fp32.
// Uncoalesced but correct.
// ---------------------------------------------------------------------------
__global__ __launch_bounds__(256) void roi_gather_direct(
    const float* __restrict__ feat, const float* __restrict__ rois,
    const int* __restrict__ bidx, float* __restrict__ out) {
  __shared__ float vals[C_ * OHW_];
  const int n = blockIdx.x;
  const int t = threadIdx.x;

  const float x1 = rois[n * 4 + 0] * SCALE_ - 0.5f;
  const float y1 = rois[n * 4 + 1] * SCALE_ - 0.5f;
  const float x2 = rois[n * 4 + 2] * SCALE_ - 0.5f;
  const float y2 = rois[n * 4 + 3] * SCALE_ - 0.5f;
  const float bw = (x2 - x1) * (1.0f / OW_);
  const float bh = (y2 - y1) * (1.0f / OH_);
  const int b = bidx[n];
  const float* fc = feat + ((size_t)b * C_ + t) * HW_;

  for (int s = 0; s < OHW_; ++s) {
    const int oh = s / OW_, ow = s % OW_;
    const float y = y1 + ((float)oh + 0.5f) * bh;
    const float x = x1 + ((float)ow + 0.5f) * bw;
    const bool valid =
        (y >= -1.0f) & (y <= (float)H_) & (x >= -1.0f) & (x <= (float)W_);
    const float yc = fminf(fmaxf(y, 0.0f), (float)(H_ - 1));
    const float xc = fminf(fmaxf(x, 0.0f), (float)(W_ - 1));
    const int yl = (int)yc;
    const int xl = (int)xc;
    const int yh = min(yl + 1, H_ - 1);
    const int xh = min(xl + 1, W_ - 1);
    const float ly = yc - (float)yl, lx = xc - (float)xl;
    const float hy = 1.0f - ly, hx = 1.0f - lx;

    float v = hy * hx * fc[yl * W_ + xl] + hy * lx * fc[yl * W_ + xh] +
              ly * hx * fc[yh * W_ + xl] + ly * lx * fc[yh * W_ + xh];
    vals[t * OHW_ + s] = valid ? v : 0.0f;
  }
  __syncthreads();

  float* po = out + (size_t)n * (C_ * OHW_);
#pragma unroll
  for (int k = 0; k < OHW_; ++k) {
    po[k * C_ + t] = vals[k * C_ + t];
  }
}

extern "C" void kernel_launch(void* const* d_in, const int* in_sizes, int n_in,
                              void* d_out, int out_size, void* d_ws,
                              size_t ws_size, hipStream_t stream) {
  const float* feat = (const float*)d_in[0];
  const float* rois = (const float*)d_in[1];
  const int*   bidx = (const int*)d_in[2];
  float*       out  = (float*)d_out;
  const int nrois = in_sizes[1] / 4;

  const size_t need = (size_t)PB_ * HW_ * C_ * sizeof(__half);  // ~69 MB
  if (ws_size >= need) {
    __half* featT = (__half*)d_ws;
    for (int b0 = 0; b0 < B_; b0 += PB_) {
      dim3 tg(HW_ / 32, C_ / 128, PB_);  // (2100, 2, 2)
      transpose_bchw_bhwc_f16<<<tg, 256, 0, stream>>>(feat, featT, b0);
      dim3 gg(nrois, 2, 1);
      roi_gather_T_f16<<<gg, 256, 0, stream>>>(featT, rois, bidx, out, b0);
    }
  } else {
    roi_gather_direct<<<nrois, 256, 0, stream>>>(feat, rois, bidx, out);
  }
}

// Round 8
// 111.669 us; speedup vs baseline: 1.0763x; 1.0763x over previous
//
#include <hip/hip_runtime.h>
#include <hip/hip_bf16.h>
#include <hip/hip_fp16.h>

// Problem constants (fixed by reference setup_inputs)
constexpr int B_ = 4, C_ = 256, H_ = 200, W_ = 336;
constexpr int OH_ = 7, OW_ = 7;
constexpr float SCALE_ = 0.25f;
constexpr int HW_ = H_ * W_;          // 67200
constexpr int OHW_ = OH_ * OW_;       // 49
constexpr int CH_ = 128;              // channels per gather block (C_/2)

typedef float f32x4 __attribute__((ext_vector_type(4)));

// ---------------------------------------------------------------------------
// HBM traffic model (measured-consistent, R6 = 111.6 us):
//   transpose: 275 MB read + 137 MB write = 412 MB  (~64 us)
//   gather:    205 MB corner reads + 98 MB out      (~47 us)
//   total ~715 MB @ ~6.45 TB/s mixed  => ~111 us  == measured.
// R7 falsified the L3-residency lever (69 MB phased featT: no gain).
// ---------------------------------------------------------------------------

// Kernel 1: transpose+downconvert (B, C, H*W) fp32 -> (B, H*W, C) fp16.
// Read: scalar nontemporal loads, 128B/wave-row segments; conversion fused
// (each thread packs a channel pair into a __half2/uint). Write: uint4
// stores, 256B segments. BW-bound; VALU ~6x under the byte budget.
__global__ __launch_bounds__(256) void transpose_bchw_bhwc_f16(
    const float* __restrict__ in, __half* __restrict__ out) {
  __shared__ unsigned int tileu[32][68];  // [k][cu]; uint = 2 channels
  const int b  = blockIdx.z;
  const int k0 = blockIdx.x * 32;   // spatial tile origin
  const int c0 = blockIdx.y * 128;  // channel tile origin
  const float* src = in + (size_t)b * C_ * HW_;
  unsigned int* dst = (unsigned int*)(out + (size_t)b * HW_ * C_);

  const int tx = threadIdx.x & 31;  // k within tile
  const int rp = threadIdx.x >> 5;  // 0..7
#pragma unroll
  for (int i = 0; i < 8; ++i) {
    const int cu = rp * 8 + i;      // channel pair 0..63
    const float a = __builtin_nontemporal_load(
        &src[(size_t)(c0 + 2 * cu) * HW_ + k0 + tx]);
    const float c = __builtin_nontemporal_load(
        &src[(size_t)(c0 + 2 * cu + 1) * HW_ + k0 + tx]);
    const __half2 h = __halves2half2(__float2half(a), __float2half(c));
    tileu[tx][cu] = *(const unsigned int*)&h;
  }
  __syncthreads();

  const int q  = threadIdx.x & 15;  // uint4 index within k-row
  const int kk = threadIdx.x >> 4;  // 0..15
#pragma unroll
  for (int p = 0; p < 2; ++p) {
    const int k = kk + p * 16;
    const uint4 v = *(const uint4*)&tileu[k][4 * q];
    *(uint4*)&dst[(size_t)(k0 + k) * (C_ / 2) + (c0 / 2) + 4 * q] = v;
  }
}

// Kernel 2: RoIAlign gather from fp16 (B, H, W, C) features.
// Grid (nrois, 2): block = one ROI x 128 channels. Threads 0..48
// precompute corner offsets + valid-folded bilinear weights into LDS.
// Lane cp=0..63 owns local channel pair; 4 waves stride the 49 samples;
// 4 x 256B coalesced corner loads per wave per sample. Stage in
// vals[c_local*49+s] (25 KB -> ~5 blocks/CU), stream out linear
// nontemporal f32x4 into out[n][ch0+c][s] ((N, C, OH, OW) layout).
__global__ __launch_bounds__(256) void roi_gather_T_f16(
    const __half* __restrict__ featT, const float* __restrict__ rois,
    const int* __restrict__ bidx, float* __restrict__ out) {
  __shared__ float vals[CH_ * OHW_];  // 25088 B
  __shared__ int   offs[4][OHW_];     // corner pixel index (y*W+x)
  __shared__ float wts[4][OHW_];      // bilinear weights, valid-folded
  const int n   = blockIdx.x;
  const int ch0 = blockIdx.y * CH_;   // channel half origin (0 or 128)
  const int t   = threadIdx.x;

  if (t < OHW_) {
    const int s = t, oh = s / OW_, ow = s - oh * OW_;
    const float x1 = rois[n * 4 + 0] * SCALE_ - 0.5f;
    const float y1 = rois[n * 4 + 1] * SCALE_ - 0.5f;
    const float x2 = rois[n * 4 + 2] * SCALE_ - 0.5f;
    const float y2 = rois[n * 4 + 3] * SCALE_ - 0.5f;
    const float bw = (x2 - x1) * (1.0f / OW_);
    const float bh = (y2 - y1) * (1.0f / OH_);
    const float x = x1 + ((float)ow + 0.5f) * bw;
    const float y = y1 + ((float)oh + 0.5f) * bh;
    const bool valid =
        (y >= -1.0f) & (y <= (float)H_) & (x >= -1.0f) & (x <= (float)W_);
    const float xc = fminf(fmaxf(x, 0.0f), (float)(W_ - 1));
    const float yc = fminf(fmaxf(y, 0.0f), (float)(H_ - 1));
    const int xl = (int)xc, yl = (int)yc;
    const int xh = min(xl + 1, W_ - 1), yh = min(yl + 1, H_ - 1);
    const float lx = xc - (float)xl, ly = yc - (float)yl;
    const float hx = 1.0f - lx, hy = 1.0f - ly;
    const float vm = valid ? 1.0f : 0.0f;
    offs[0][s] = yl * W_ + xl;  wts[0][s] = vm * hy * hx;
    offs[1][s] = yl * W_ + xh;  wts[1][s] = vm * hy * lx;
    offs[2][s] = yh * W_ + xl;  wts[2][s] = vm * ly * hx;
    offs[3][s] = yh * W_ + xh;  wts[3][s] = vm * ly * lx;
  }
  __syncthreads();

  const int b = bidx[n];
  const __half2* fb2 =
      (const __half2*)(featT + (size_t)b * HW_ * C_) + (ch0 >> 1);
  const int cp = t & 63;   // local channel pair -> channels 2cp, 2cp+1
  const int sh = t >> 6;   // sample phase 0..3 (wave-uniform)

#pragma unroll 2
  for (int i = 0; i < 13; ++i) {
    const int s = 4 * i + sh;
    if (s < OHW_) {
      const float w0 = wts[0][s], w1 = wts[1][s];
      const float w2 = wts[2][s], w3 = wts[3][s];
      const __half2 a0 = fb2[(size_t)offs[0][s] * (C_ / 2) + cp];
      const __half2 a1 = fb2[(size_t)offs[1][s] * (C_ / 2) + cp];
      const __half2 a2 = fb2[(size_t)offs[2][s] * (C_ / 2) + cp];
      const __half2 a3 = fb2[(size_t)offs[3][s] * (C_ / 2) + cp];
      const float2 f0 = __half22float2(a0), f1 = __half22float2(a1);
      const float2 f2 = __half22float2(a2), f3 = __half22float2(a3);
      vals[(2 * cp)     * OHW_ + s] =
          w0 * f0.x + w1 * f1.x + w2 * f2.x + w3 * f3.x;
      vals[(2 * cp + 1) * OHW_ + s] =
          w0 * f0.y + w1 * f1.y + w2 * f2.y + w3 * f3.y;
    }
  }
  __syncthreads();

  // Stream out 6272 floats (= 1568 f32x4) -> out[n][ch0..ch0+127][:],
  // contiguous, nontemporal (never re-read).
  const f32x4* v4 = (const f32x4*)vals;
  float* po = out + (size_t)n * (C_ * OHW_) + (size_t)ch0 * OHW_;
#pragma unroll
  for (int p = 0; p < 7; ++p) {
    const int idx = p * 256 + t;
    if (idx < (CH_ * OHW_) / 4) {
      __builtin_nontemporal_store(v4[idx], (f32x4*)&po[idx * 4]);
    }
  }
}

// Fallback (only if ws too small): gather straight from (B, C, H, W) fp32.
__global__ __launch_bounds__(256) void roi_gather_direct(
    const float* __restrict__ feat, const float* __restrict__ rois,
    const int* __restrict__ bidx, float* __restrict__ out) {
  __shared__ float vals[C_ * OHW_];
  const int n = blockIdx.x;
  const int t = threadIdx.x;

  const float x1 = rois[n * 4 + 0] * SCALE_ - 0.5f;
  const float y1 = rois[n * 4 + 1] * SCALE_ - 0.5f;
  const float x2 = rois[n * 4 + 2] * SCALE_ - 0.5f;
  const float y2 = rois[n * 4 + 3] * SCALE_ - 0.5f;
  const float bw = (x2 - x1) * (1.0f / OW_);
  const float bh = (y2 - y1) * (1.0f / OH_);
  const int b = bidx[n];
  const float* fc = feat + ((size_t)b * C_ + t) * HW_;

  for (int s = 0; s < OHW_; ++s) {
    const int oh = s / OW_, ow = s % OW_;
    const float y = y1 + ((float)oh + 0.5f) * bh;
    const float x = x1 + ((float)ow + 0.5f) * bw;
    const bool valid =
        (y >= -1.0f) & (y <= (float)H_) & (x >= -1.0f) & (x <= (float)W_);
    const float yc = fminf(fmaxf(y, 0.0f), (float)(H_ - 1));
    const float xc = fminf(fmaxf(x, 0.0f), (float)(W_ - 1));
    const int yl = (int)yc;
    const int xl = (int)xc;
    const int yh = min(yl + 1, H_ - 1);
    const int xh = min(xl + 1, W_ - 1);
    const float ly = yc - (float)yl, lx = xc - (float)xl;
    const float hy = 1.0f - ly, hx = 1.0f - lx;

    float v = hy * hx * fc[yl * W_ + xl] + hy * lx * fc[yl * W_ + xh] +
              ly * hx * fc[yh * W_ + xl] + ly * lx * fc[yh * W_ + xh];
    vals[t * OHW_ + s] = valid ? v : 0.0f;
  }
  __syncthreads();

  float* po = out + (size_t)n * (C_ * OHW_);
#pragma unroll
  for (int k = 0; k < OHW_; ++k) {
    po[k * C_ + t] = vals[k * C_ + t];
  }
}

extern "C" void kernel_launch(void* const* d_in, const int* in_sizes, int n_in,
                              void* d_out, int out_size, void* d_ws,
                              size_t ws_size, hipStream_t stream) {
  const float* feat = (const float*)d_in[0];
  const float* rois = (const float*)d_in[1];
  const int*   bidx = (const int*)d_in[2];
  float*       out  = (float*)d_out;
  const int nrois = in_sizes[1] / 4;

  const size_t need = (size_t)B_ * HW_ * C_ * sizeof(__half);  // ~137 MB
  if (ws_size >= need) {
    __half* featT = (__half*)d_ws;
    dim3 tg(HW_ / 32, C_ / 128, B_);  // (2100, 2, 4)
    transpose_bchw_bhwc_f16<<<tg, 256, 0, stream>>>(feat, featT);
    dim3 gg(nrois, 2, 1);
    roi_gather_T_f16<<<gg, 256, 0, stream>>>(featT, rois, bidx, out);
  } else {
    roi_gather_direct<<<nrois, 256, 0, stream>>>(feat, rois, bidx, out);
  }
}